// Round 1
// 21592.859 us; speedup vs baseline: 1.0060x; 1.0060x over previous
//
#include <hip/hip_runtime.h>
#include <math.h>

#define BB 256
#define TT 100
#define DD 784
#define HH 128
#define NEGV -1e9f
#define NT 1024

struct Params {
  const float *x, *gum;
  const float *W1, *b1, *W2, *b2, *W3, *b3, *W4, *b4;
  const float *Wf2, *bf2, *Wg1, *bg1, *Wg2, *bg2;
  const float *Wih, *Whh, *bih, *bhh;
  unsigned* bar;   // 256 flags, 128B apart (32 KB)
  float* wsf;      // float workspace after flags
  int* ilist;      // [256][128] sampled-pixel indices
  float* out;      // [B,10,T]
};

__device__ __forceinline__ float leaky_(float v) { return v > 0.f ? v : 0.2f * v; }
__device__ __forceinline__ float sigm_(float v)  { return 1.f / (1.f + expf(-v)); }

__device__ __forceinline__ float4 sx4(float4 v, int m) {
  v.x = __shfl_xor(v.x, m); v.y = __shfl_xor(v.y, m);
  v.z = __shfl_xor(v.z, m); v.w = __shfl_xor(v.w, m);
  return v;
}

// 16-WG group barrier: monotonic per-WG flags (no RMW contention).
__device__ __forceinline__ void group_barrier(unsigned* bar, int rb, int wg, int tid, int barn) {
  __syncthreads();
  if (tid < 64) {
    if (tid == 0) {
      __threadfence();
      __hip_atomic_store(bar + wg * 32, (unsigned)barn, __ATOMIC_RELEASE, __HIP_MEMORY_SCOPE_AGENT);
    }
    const unsigned tgt = (unsigned)barn;
    unsigned long long spin = 0;
    for (;;) {
      unsigned v = tgt;
      if (tid < 16)
        v = __hip_atomic_load(bar + (rb * 16 + tid) * 32, __ATOMIC_RELAXED, __HIP_MEMORY_SCOPE_AGENT);
      if ((__ballot(v >= tgt) & 0xFFFFull) == 0xFFFFull) break;
      if (++spin > (1ull << 23)) break;  // safety valve (never hit in practice)
    }
    __threadfence();
  }
  __syncthreads();
}

// Dense layer, 1024 threads: 16 rows (LDS-staged) x CWG cols per WG.
// Lane layout: bl = tid>>6 (row, wave-uniform), qd = (tid&63)/KC (col quad),
// kc = (tid&63)&(KC-1) (K-slice, LOW lane bits -> shuffle reduce, no LDS).
template <int K, int CTOT, int CWG, bool LEAKY>
__device__ __forceinline__ void dense_shfl(const float* sin, const float* W,
                                           const float* bias, float* outbuf,
                                           int row0, int cb, int tid) {
  constexpr int NQ = CWG / 4;       // 4 or 2 quads per WG
  constexpr int KC = 64 / NQ;       // 16 or 32 K-slices
  constexpr int KLEN = K / KC;
  const int bl = tid >> 6;
  const int rem = tid & 63;
  const int qd = rem / KC;
  const int kc = rem & (KC - 1);
  const int c0 = cb * CWG + qd * 4;
  const float* ip = sin + bl * K;
  const float* wp = W + c0;
  float4 acc = make_float4(0.f, 0.f, 0.f, 0.f);
#pragma unroll 4
  for (int i = 0; i < KLEN; ++i) {
    const int k = kc + i * KC;                 // interleaved: conflict-free LDS
    const float v = ip[k];
    const float4 w4 = *reinterpret_cast<const float4*>(wp + (size_t)k * CTOT);
    acc.x += v * w4.x; acc.y += v * w4.y; acc.z += v * w4.z; acc.w += v * w4.w;
  }
#pragma unroll
  for (int m = 1; m < KC; m <<= 1) {
    const float4 o = sx4(acc, m);
    acc.x += o.x; acc.y += o.y; acc.z += o.z; acc.w += o.w;
  }
  if (kc == 0) {
    const float4 b4 = *reinterpret_cast<const float4*>(bias + c0);
    acc.x += b4.x; acc.y += b4.y; acc.z += b4.z; acc.w += b4.w;
    if (LEAKY) { acc.x = leaky_(acc.x); acc.y = leaky_(acc.y); acc.z = leaky_(acc.z); acc.w = leaky_(acc.w); }
    *reinterpret_cast<float4*>(outbuf + (size_t)(row0 + bl) * CTOT + c0) = acc;
  }
}

__global__ __launch_bounds__(NT, 4) void net_kernel(Params p) {
  __shared__ float smem[16 * DD];   // 50176 B staging (sgate overlaps tail)
  __shared__ float rv[16];
  __shared__ int   ri[16];

  const int tid = threadIdx.x;
  const int wg = blockIdx.x;
  const int rb = wg >> 4;    // row group (16 rows)
  const int cb = wg & 15;    // column-slice id within group
  const int row0 = rb * 16;

  float* h0  = p.wsf;
  float* h1  = h0 + BB * HH;
  float* cst = h1 + BB * HH;
  float* aa  = cst + BB * HH;      // lin (LSTM input) = previous step's a
  float* mem = aa + BB * HH;       // [B,784] sampled mask
  float* g1b = mem + BB * DD;      // [B,256]
  float* prt = g1b + BB * 256;     // [B,784] perturbed logits
  float* t1b = prt + BB * DD;      // [B,784]
  float* t2b = t1b + BB * DD;      // [B,256]
  float* t3b = t2b + BB * 256;     // [B,128]

  int barn = 0;

  for (int t = 0; t < TT; ++t) {
    float* hprev = (t & 1) ? h1 : h0;
    float* hnew  = (t & 1) ? h0 : h1;

    // ===== ph1: LSTM gates -> h,c ; plus s(t-1) = a @ Wf2 =====
    {  // stage aa -> smem[0..2047], hprev -> smem[2048..4095] (float4)
      const int i = tid & 511;
      const int r = i >> 5, c = i & 31;
      const float* src = (tid < 512) ? aa : hprev;
      reinterpret_cast<float4*>(smem)[tid] =
          *reinterpret_cast<const float4*>(src + (size_t)(row0 + r) * HH + c * 4);
    }
    __syncthreads();
    float* sgate = smem + 2 * 16 * HH;  // 512 floats
    {
      const int bl = tid >> 6;
      const int rem = tid & 63;
      const int u = rem >> 3;          // 8 units: q (gate), cq (col quad)
      const int q = u >> 1, cq = u & 1;
      const int kc = rem & 7;          // 8 K-slices of K=128
      const int col4 = cb * 8 + cq * 4;
      const float* sa = smem + bl * HH;
      const float* sh = smem + 2048 + bl * HH;
      const float* wi = p.Wih + q * 128 + col4;
      const float* wh = p.Whh + q * 128 + col4;
      float4 acc = make_float4(0.f, 0.f, 0.f, 0.f);
#pragma unroll 4
      for (int i = 0; i < 16; ++i) {
        const int k = kc + i * 8;
        const float av = sa[k], hv = sh[k];
        const float4 wiv = *reinterpret_cast<const float4*>(wi + (size_t)k * 512);
        const float4 whv = *reinterpret_cast<const float4*>(wh + (size_t)k * 512);
        acc.x += av * wiv.x + hv * whv.x;
        acc.y += av * wiv.y + hv * whv.y;
        acc.z += av * wiv.z + hv * whv.z;
        acc.w += av * wiv.w + hv * whv.w;
      }
#pragma unroll
      for (int m = 1; m < 8; m <<= 1) {
        const float4 o = sx4(acc, m);
        acc.x += o.x; acc.y += o.y; acc.z += o.z; acc.w += o.w;
      }
      if (kc == 0) {
        const int bc = q * 128 + col4;
        const float4 bi4 = *reinterpret_cast<const float4*>(p.bih + bc);
        const float4 bh4 = *reinterpret_cast<const float4*>(p.bhh + bc);
        acc.x += bi4.x + bh4.x; acc.y += bi4.y + bh4.y;
        acc.z += bi4.z + bh4.z; acc.w += bi4.w + bh4.w;
        *reinterpret_cast<float4*>(sgate + ((q * 16 + bl) * 8 + cq * 4)) = acc;
      }
    }
    __syncthreads();
    if (tid < 128) {                 // c/h update
      const int bl = tid >> 3, jl = tid & 7;
      const int col = cb * 8 + jl;
      const int b = row0 + bl;
      const float gi = sgate[(0 * 16 + bl) * 8 + jl];
      const float gf = sgate[(1 * 16 + bl) * 8 + jl];
      const float gg = sgate[(2 * 16 + bl) * 8 + jl];
      const float go = sgate[(3 * 16 + bl) * 8 + jl];
      const float cv = cst[(size_t)b * HH + col];
      const float cn = sigm_(gf) * cv + sigm_(gi) * tanhf(gg);
      const float hn = sigm_(go) * tanhf(cn);
      cst[(size_t)b * HH + col]  = cn;
      hnew[(size_t)b * HH + col] = hn;
    } else if (tid < 168 && t > 0) { // s(t-1): this WG handles row cb (40 threads)
      const int u = tid - 128;       // wave 2, lanes 0..39
      const int sc = u >> 2;
      const int kc = u & 3;
      const float* sa = smem + cb * HH;   // aa row cb, still staged
      const float* w = p.Wf2 + (size_t)(t - 1) * HH * 10 + sc;
      float acc = 0.f;
#pragma unroll 8
      for (int k = kc; k < HH; k += 4) acc += sa[k] * w[(size_t)k * 10];
      acc += __shfl_xor(acc, 1);
      acc += __shfl_xor(acc, 2);
      if (kc == 0)
        p.out[(size_t)(row0 + cb) * 1000 + sc * 100 + (t - 1)] = acc + p.bf2[(t - 1) * 10 + sc];
    }
    group_barrier(p.bar, rb, wg, tid, ++barn);

    // ===== ph2: g1 = leaky(h @ Wg1 + bg1) =====
    if (tid < 512) {
      const int r = tid >> 5, c = tid & 31;
      reinterpret_cast<float4*>(smem)[tid] =
          *reinterpret_cast<const float4*>(hnew + (size_t)(row0 + r) * HH + c * 4);
    }
    __syncthreads();
    dense_shfl<HH, 256, 16, true>(smem, p.Wg1 + (size_t)t * HH * 256,
                                  p.bg1 + (size_t)t * 256, g1b, row0, cb, tid);
    group_barrier(p.bar, rb, wg, tid, ++barn);

    // ===== ph3: pert = mem>0 ? NEG : g1 @ Wg2 + bg2 + gumbel =====
    {
      const int r = tid >> 6, c = tid & 63;
      reinterpret_cast<float4*>(smem)[tid] =
          *reinterpret_cast<const float4*>(g1b + (size_t)(row0 + r) * 256 + c * 4);
    }
    __syncthreads();
    {
      const int bl = tid >> 6;
      const int rem = tid & 63;
      const int s = rem >> 2;          // quad slot 0..15
      const int kc = rem & 3;          // 4 K-slices of K=256
      int q = -1;                      // quad id 0..195
      if (s < 12) q = cb * 12 + s;
      else if (s == 12 && cb < 4) q = 192 + cb;
      float4 acc = make_float4(0.f, 0.f, 0.f, 0.f);
      if (q >= 0) {
        const int c0 = q * 4;
        const float* sg = smem + bl * 256;
        const float* w = p.Wg2 + (size_t)t * 256 * DD + c0;
#pragma unroll 4
        for (int i = 0; i < 64; ++i) {
          const int k = kc + i * 4;
          const float gv = sg[k];
          const float4 w4 = *reinterpret_cast<const float4*>(w + (size_t)k * DD);
          acc.x += gv * w4.x; acc.y += gv * w4.y; acc.z += gv * w4.z; acc.w += gv * w4.w;
        }
      }
      {
        float4 o = sx4(acc, 1); acc.x += o.x; acc.y += o.y; acc.z += o.z; acc.w += o.w;
        o = sx4(acc, 2);        acc.x += o.x; acc.y += o.y; acc.z += o.z; acc.w += o.w;
      }
      if (q >= 0 && kc == 0) {
        const int b = row0 + bl;
        const int c0 = q * 4;
        const float4 b4 = *reinterpret_cast<const float4*>(p.bg2 + (size_t)t * DD + c0);
        const float4 g4 = *reinterpret_cast<const float4*>(p.gum + ((size_t)t * BB + b) * DD + c0);
        const float4 m4 = *reinterpret_cast<const float4*>(mem + (size_t)b * DD + c0);
        float4 r4;
        r4.x = m4.x > 0.f ? NEGV : acc.x + b4.x + g4.x;
        r4.y = m4.y > 0.f ? NEGV : acc.y + b4.y + g4.y;
        r4.z = m4.z > 0.f ? NEGV : acc.z + b4.z + g4.z;
        r4.w = m4.w > 0.f ? NEGV : acc.w + b4.w + g4.w;
        *reinterpret_cast<float4*>(prt + (size_t)b * DD + c0) = r4;
      }
    }
    group_barrier(p.bar, rb, wg, tid, ++barn);

    // ===== ph4: per-row argmax (first-index ties), mem/ilist update =====
    {
      const int b = row0 + cb;   // one row per WG within the group
      const float* pr = prt + (size_t)b * DD;
      float bv = -1e30f; int bi = DD;
      if (tid < DD) { bv = pr[tid]; bi = tid; }
#pragma unroll
      for (int m = 1; m < 64; m <<= 1) {
        const float ov = __shfl_xor(bv, m);
        const int   oi = __shfl_xor(bi, m);
        if (ov > bv || (ov == bv && oi < bi)) { bv = ov; bi = oi; }
      }
      const int wid = tid >> 6;
      if ((tid & 63) == 0) { rv[wid] = bv; ri[wid] = bi; }
      __syncthreads();
      if (tid < 16) {
        bv = rv[tid]; bi = ri[tid];
#pragma unroll
        for (int m = 1; m < 16; m <<= 1) {
          const float ov = __shfl_xor(bv, m);
          const int   oi = __shfl_xor(bi, m);
          if (ov > bv || (ov == bv && oi < bi)) { bv = ov; bi = oi; }
        }
        if (tid == 0) {
          mem[(size_t)b * DD + bi] = 1.f;
          p.ilist[b * 128 + t] = bi;
        }
      }
    }
    group_barrier(p.bar, rb, wg, tid, ++barn);

    // ===== ph5: t1 = leaky(y @ W1 + b1), SPARSE over t+1 sampled pixels =====
    {
      int* sidx = reinterpret_cast<int*>(smem);
      float* sval = smem + 1664;
      const int nnz = t + 1;
      for (int i = tid; i < 16 * nnz; i += NT) {
        const int r = i / nnz, n = i - r * nnz;
        const int kk = p.ilist[(row0 + r) * 128 + n];
        sidx[r * 100 + n] = kk;
        sval[r * 100 + n] = p.x[(size_t)(row0 + r) * DD + kk];
      }
      __syncthreads();
      const int bl = tid >> 6;
      const int rem = tid & 63;
      const int s = rem >> 2;
      const int kc = rem & 3;          // 4-way split of nnz list
      int q = -1;
      if (s < 12) q = cb * 12 + s;
      else if (s == 12 && cb < 4) q = 192 + cb;
      float4 acc = make_float4(0.f, 0.f, 0.f, 0.f);
      if (q >= 0) {
        const int c0 = q * 4;
        const float* w = p.W1 + (size_t)t * DD * DD + c0;
        const int* si = sidx + bl * 100;
        const float* sv = sval + bl * 100;
        for (int n = kc; n < nnz; n += 4) {
          const float yv = sv[n];
          const float4 w4 = *reinterpret_cast<const float4*>(w + (size_t)si[n] * DD);
          acc.x += yv * w4.x; acc.y += yv * w4.y; acc.z += yv * w4.z; acc.w += yv * w4.w;
        }
      }
      {
        float4 o = sx4(acc, 1); acc.x += o.x; acc.y += o.y; acc.z += o.z; acc.w += o.w;
        o = sx4(acc, 2);        acc.x += o.x; acc.y += o.y; acc.z += o.z; acc.w += o.w;
      }
      if (q >= 0 && kc == 0) {
        const int c0 = q * 4;
        const float4 b4 = *reinterpret_cast<const float4*>(p.b1 + (size_t)t * DD + c0);
        float4 o4;
        o4.x = leaky_(acc.x + b4.x); o4.y = leaky_(acc.y + b4.y);
        o4.z = leaky_(acc.z + b4.z); o4.w = leaky_(acc.w + b4.w);
        *reinterpret_cast<float4*>(t1b + (size_t)(row0 + bl) * DD + c0) = o4;
      }
    }
    group_barrier(p.bar, rb, wg, tid, ++barn);

    // ===== ph6: t2 = leaky(t1 @ W2 + b2) =====
    for (int i = tid; i < 16 * 196; i += NT) {
      const int r = i / 196, c = i - r * 196;
      reinterpret_cast<float4*>(smem)[i] =
          *reinterpret_cast<const float4*>(t1b + (size_t)(row0 + r) * DD + c * 4);
    }
    __syncthreads();
    dense_shfl<DD, 256, 16, true>(smem, p.W2 + (size_t)t * DD * 256,
                                  p.b2 + (size_t)t * 256, t2b, row0, cb, tid);
    group_barrier(p.bar, rb, wg, tid, ++barn);

    // ===== ph7: t3 = leaky(t2 @ W3 + b3) =====
    {
      const int r = tid >> 6, c = tid & 63;
      reinterpret_cast<float4*>(smem)[tid] =
          *reinterpret_cast<const float4*>(t2b + (size_t)(row0 + r) * 256 + c * 4);
    }
    __syncthreads();
    dense_shfl<256, HH, 8, true>(smem, p.W3 + (size_t)t * 256 * HH,
                                 p.b3 + (size_t)t * HH, t3b, row0, cb, tid);
    group_barrier(p.bar, rb, wg, tid, ++barn);

    // ===== ph8: a = leaky(t3 @ W4 + b4) =====
    if (tid < 512) {
      const int r = tid >> 5, c = tid & 31;
      reinterpret_cast<float4*>(smem)[tid] =
          *reinterpret_cast<const float4*>(t3b + (size_t)(row0 + r) * HH + c * 4);
    }
    __syncthreads();
    dense_shfl<HH, HH, 8, true>(smem, p.W4 + (size_t)t * HH * HH,
                                p.b4 + (size_t)t * HH, aa, row0, cb, tid);
    group_barrier(p.bar, rb, wg, tid, ++barn);
  }

  // ===== final s(99): each WG handles row cb, read aa from global =====
  if (tid < 40) {
    const int sc = tid >> 2;
    const int kc = tid & 3;
    const float* ar = aa + (size_t)(row0 + cb) * HH;
    const float* w = p.Wf2 + (size_t)99 * HH * 10 + sc;
    float acc = 0.f;
#pragma unroll 8
    for (int k = kc; k < HH; k += 4) acc += ar[k] * w[(size_t)k * 10];
    acc += __shfl_xor(acc, 1);
    acc += __shfl_xor(acc, 2);
    if (kc == 0)
      p.out[(size_t)(row0 + cb) * 1000 + sc * 100 + 99] = acc + p.bf2[99 * 10 + sc];
  }
}

extern "C" void kernel_launch(void* const* d_in, const int* in_sizes, int n_in,
                              void* d_out, int out_size, void* d_ws, size_t ws_size,
                              hipStream_t stream) {
  (void)in_sizes; (void)n_in; (void)out_size; (void)ws_size;
  Params p;
  p.x   = (const float*)d_in[0];
  p.gum = (const float*)d_in[1];
  p.W1  = (const float*)d_in[2];  p.b1  = (const float*)d_in[3];
  p.W2  = (const float*)d_in[4];  p.b2  = (const float*)d_in[5];
  p.W3  = (const float*)d_in[6];  p.b3  = (const float*)d_in[7];
  p.W4  = (const float*)d_in[8];  p.b4  = (const float*)d_in[9];
  p.Wf2 = (const float*)d_in[10]; p.bf2 = (const float*)d_in[11];
  p.Wg1 = (const float*)d_in[12]; p.bg1 = (const float*)d_in[13];
  p.Wg2 = (const float*)d_in[14]; p.bg2 = (const float*)d_in[15];
  p.Wih = (const float*)d_in[16]; p.Whh = (const float*)d_in[17];
  p.bih = (const float*)d_in[18]; p.bhh = (const float*)d_in[19];
  p.bar = (unsigned*)d_ws;
  p.wsf = (float*)((char*)d_ws + 32768);
  p.ilist = (int*)(p.wsf + 897024);
  p.out = (float*)d_out;
  // zero: barrier flags (32KB) + h0,h1,c,a (4*128KB) + mem (784KB)
  hipMemsetAsync(d_ws, 0, 1359872, stream);
  hipLaunchKernelGGL(net_kernel, dim3(256), dim3(NT), 0, stream, p);
}

// Round 2
// 9094.646 us; speedup vs baseline: 2.3884x; 2.3742x over previous
//
#include <hip/hip_runtime.h>
#include <math.h>

#define BB 256
#define TT 100
#define DD 784
#define HH 128
#define NEGV -1e9f
#define NT 1024

struct Params {
  const float *x, *gum;
  const float *W1, *b1, *W2, *b2, *W3, *b3, *W4, *b4;
  const float *Wf2, *bf2, *Wg1, *bg1, *Wg2, *bg2;
  const float *Wih, *Whh, *bih, *bhh;
  float* out;      // [B,10,T]
};

__device__ __forceinline__ float leaky_(float v) { return v > 0.f ? v : 0.2f * v; }
__device__ __forceinline__ float sigm_(float v)  { return 1.f / (1.f + expf(-v)); }

// One batch row per WG. All carry state lives in LDS; no inter-WG sync at all.
// All 256 WGs stream the same per-step weight panels (~2.7 MB) in near-lockstep,
// so panels stay L2-resident (never invalidated: no agent fences anywhere).
__global__ __launch_bounds__(NT, 4) void net_kernel(Params p) {
  __shared__ float part[4096];          // K-split partials (max [16][64] float4)
  __shared__ float xld[DD];             // x row
  __shared__ float memld[DD];           // sampled mask
  __shared__ float pert[DD];
  __shared__ float t1b[DD];
  __shared__ float g1b[256];
  __shared__ float t2b[256];
  __shared__ float t3b[HH];
  __shared__ float hld[HH], cld[HH], ald[HH];
  __shared__ float gates[512];
  __shared__ int   idxld[TT];           // sampled pixel per step
  __shared__ float wrv[16];
  __shared__ int   wri[16];

  const int tid = threadIdx.x;
  const int b = blockIdx.x;

  // ---- init state ----
  if (tid < HH) { hld[tid] = 0.f; cld[tid] = 0.f; ald[tid] = 0.f; }
  if (tid < DD) memld[tid] = 0.f;
  if (tid < DD / 4)
    reinterpret_cast<float4*>(xld)[tid] =
        reinterpret_cast<const float4*>(p.x + (size_t)b * DD)[tid];
  float bsum = 0.f;
  if (tid < 512) bsum = p.bih[tid] + p.bhh[tid];   // t-independent, keep in reg
  __syncthreads();

  for (int t = 0; t < TT; ++t) {
    // ===== ph1: gates = a@Wih + h@Whh + bih + bhh ; c,h update =====
    {
      const int cq = tid & 127;         // col quad (512 cols)
      const int kc = tid >> 7;          // 8 K-slices of K=128 -> 16 each
      const float* wi = p.Wih + cq * 4;
      const float* wh = p.Whh + cq * 4;
      float4 acc = make_float4(0.f, 0.f, 0.f, 0.f);
#pragma unroll
      for (int i = 0; i < 16; ++i) {
        const int k = kc * 16 + i;
        const float av = ald[k], hv = hld[k];
        const float4 wiv = *reinterpret_cast<const float4*>(wi + (size_t)k * 512);
        const float4 whv = *reinterpret_cast<const float4*>(wh + (size_t)k * 512);
        acc.x += av * wiv.x + hv * whv.x;
        acc.y += av * wiv.y + hv * whv.y;
        acc.z += av * wiv.z + hv * whv.z;
        acc.w += av * wiv.w + hv * whv.w;
      }
      reinterpret_cast<float4*>(part)[kc * 128 + cq] = acc;
    }
    __syncthreads();
    if (tid < 512) {
      float s = bsum;
#pragma unroll
      for (int kc = 0; kc < 8; ++kc) s += part[kc * 512 + tid];
      gates[tid] = s;
    }
    __syncthreads();
    if (tid < HH) {
      const float gi = gates[tid], gf = gates[HH + tid];
      const float gg = gates[2 * HH + tid], go = gates[3 * HH + tid];
      const float cn = sigm_(gf) * cld[tid] + sigm_(gi) * tanhf(gg);
      cld[tid] = cn;
      hld[tid] = sigm_(go) * tanhf(cn);
    }
    __syncthreads();

    // ===== ph2: g1 = leaky(h @ Wg1 + bg1) [256], K=128 =====
    {
      const int cq = tid & 63;          // 64 col quads
      const int kc = tid >> 6;          // 16 K-slices -> 8 each
      const float* w = p.Wg1 + (size_t)t * HH * 256 + cq * 4;
      float4 acc = make_float4(0.f, 0.f, 0.f, 0.f);
#pragma unroll
      for (int i = 0; i < 8; ++i) {
        const int k = kc * 8 + i;
        const float hv = hld[k];
        const float4 w4 = *reinterpret_cast<const float4*>(w + (size_t)k * 256);
        acc.x += hv * w4.x; acc.y += hv * w4.y; acc.z += hv * w4.z; acc.w += hv * w4.w;
      }
      reinterpret_cast<float4*>(part)[kc * 64 + cq] = acc;
    }
    __syncthreads();
    if (tid < 256) {
      float s = p.bg1[(size_t)t * 256 + tid];
#pragma unroll
      for (int kc = 0; kc < 16; ++kc) s += part[kc * 256 + tid];
      g1b[tid] = leaky_(s);
    }
    __syncthreads();

    // ===== ph3: pert = mem>0 ? NEG : g1@Wg2 + bg2 + gumbel [784], K=256 =====
    {
      const int cq = tid & 255;         // 196 valid col quads
      const int kc = tid >> 8;          // 4 K-slices -> 64 each
      if (cq < 196) {
        const float* w = p.Wg2 + (size_t)t * 256 * DD + cq * 4;
        float4 acc = make_float4(0.f, 0.f, 0.f, 0.f);
#pragma unroll 8
        for (int i = 0; i < 64; ++i) {
          const int k = kc * 64 + i;
          const float gv = g1b[k];
          const float4 w4 = *reinterpret_cast<const float4*>(w + (size_t)k * DD);
          acc.x += gv * w4.x; acc.y += gv * w4.y; acc.z += gv * w4.z; acc.w += gv * w4.w;
        }
        reinterpret_cast<float4*>(part)[kc * 256 + cq] = acc;
      }
    }
    __syncthreads();
    if (tid < DD) {
      float s = part[tid] + part[1024 + tid] + part[2048 + tid] + part[3072 + tid];
      s += p.bg2[(size_t)t * DD + tid] + p.gum[((size_t)t * BB + b) * DD + tid];
      pert[tid] = memld[tid] > 0.f ? NEGV : s;
    }
    __syncthreads();

    // ===== ph4: argmax over pert (first-index ties), mem/idx update =====
    {
      float bv = -1e30f; int bi = DD;
      if (tid < DD) { bv = pert[tid]; bi = tid; }
#pragma unroll
      for (int m = 1; m < 64; m <<= 1) {
        const float ov = __shfl_xor(bv, m);
        const int   oi = __shfl_xor(bi, m);
        if (ov > bv || (ov == bv && oi < bi)) { bv = ov; bi = oi; }
      }
      if ((tid & 63) == 0) { wrv[tid >> 6] = bv; wri[tid >> 6] = bi; }
    }
    __syncthreads();
    if (tid < 16) {
      float bv = wrv[tid]; int bi = wri[tid];
#pragma unroll
      for (int m = 1; m < 16; m <<= 1) {
        const float ov = __shfl_xor(bv, m);
        const int   oi = __shfl_xor(bi, m);
        if (ov > bv || (ov == bv && oi < bi)) { bv = ov; bi = oi; }
      }
      if (tid == 0) { idxld[t] = bi; memld[bi] = 1.f; }
    }
    __syncthreads();

    // ===== ph5: t1 = leaky(y@W1 + b1), sparse over t+1 sampled pixels =====
    {
      const int cq = tid & 255;
      const int kc = tid >> 8;          // 4-way split of the nnz list
      if (cq < 196) {
        const float* w = p.W1 + (size_t)t * DD * DD + cq * 4;
        float4 acc = make_float4(0.f, 0.f, 0.f, 0.f);
        for (int n = kc; n <= t; n += 4) {
          const int j = idxld[n];
          const float xv = xld[j];
          const float4 w4 = *reinterpret_cast<const float4*>(w + (size_t)j * DD);
          acc.x += xv * w4.x; acc.y += xv * w4.y; acc.z += xv * w4.z; acc.w += xv * w4.w;
        }
        reinterpret_cast<float4*>(part)[kc * 256 + cq] = acc;
      }
    }
    __syncthreads();
    if (tid < DD) {
      float s = part[tid] + part[1024 + tid] + part[2048 + tid] + part[3072 + tid];
      t1b[tid] = leaky_(s + p.b1[(size_t)t * DD + tid]);
    }
    __syncthreads();

    // ===== ph6: t2 = leaky(t1 @ W2 + b2) [256], K=784 =====
    {
      const int cq = tid & 63;
      const int kc = tid >> 6;          // 16 K-slices of 49
      const float* w = p.W2 + (size_t)t * DD * 256 + cq * 4;
      float4 acc = make_float4(0.f, 0.f, 0.f, 0.f);
#pragma unroll 7
      for (int i = 0; i < 49; ++i) {
        const int k = kc * 49 + i;
        const float v = t1b[k];
        const float4 w4 = *reinterpret_cast<const float4*>(w + (size_t)k * 256);
        acc.x += v * w4.x; acc.y += v * w4.y; acc.z += v * w4.z; acc.w += v * w4.w;
      }
      reinterpret_cast<float4*>(part)[kc * 64 + cq] = acc;
    }
    __syncthreads();
    if (tid < 256) {
      float s = p.b2[(size_t)t * 256 + tid];
#pragma unroll
      for (int kc = 0; kc < 16; ++kc) s += part[kc * 256 + tid];
      t2b[tid] = leaky_(s);
    }
    __syncthreads();

    // ===== ph7: t3 = leaky(t2 @ W3 + b3) [128], K=256 =====
    {
      const int cq = tid & 31;
      const int kc = tid >> 5;          // 32 K-slices -> 8 each
      const float* w = p.W3 + (size_t)t * 256 * HH + cq * 4;
      float4 acc = make_float4(0.f, 0.f, 0.f, 0.f);
#pragma unroll
      for (int i = 0; i < 8; ++i) {
        const int k = kc * 8 + i;
        const float v = t2b[k];
        const float4 w4 = *reinterpret_cast<const float4*>(w + (size_t)k * HH);
        acc.x += v * w4.x; acc.y += v * w4.y; acc.z += v * w4.z; acc.w += v * w4.w;
      }
      reinterpret_cast<float4*>(part)[kc * 32 + cq] = acc;
    }
    __syncthreads();
    if (tid < HH) {
      float s = p.b3[(size_t)t * HH + tid];
#pragma unroll
      for (int kc = 0; kc < 32; ++kc) s += part[kc * 128 + tid];
      t3b[tid] = leaky_(s);
    }
    __syncthreads();

    // ===== ph8: a = leaky(t3 @ W4 + b4) [128], K=128 =====
    {
      const int cq = tid & 31;
      const int kc = tid >> 5;          // 32 K-slices -> 4 each
      const float* w = p.W4 + (size_t)t * HH * HH + cq * 4;
      float4 acc = make_float4(0.f, 0.f, 0.f, 0.f);
#pragma unroll
      for (int i = 0; i < 4; ++i) {
        const int k = kc * 4 + i;
        const float v = t3b[k];
        const float4 w4 = *reinterpret_cast<const float4*>(w + (size_t)k * HH);
        acc.x += v * w4.x; acc.y += v * w4.y; acc.z += v * w4.z; acc.w += v * w4.w;
      }
      reinterpret_cast<float4*>(part)[kc * 32 + cq] = acc;
    }
    __syncthreads();
    if (tid < HH) {
      float s = p.b4[(size_t)t * HH + tid];
#pragma unroll
      for (int kc = 0; kc < 32; ++kc) s += part[kc * 128 + tid];
      ald[tid] = leaky_(s);
    }
    __syncthreads();

    // ===== s(t) = a @ Wf2 + bf2 -> out[b,:,t]  (tiny, 80 threads) =====
    if (tid < 80) {
      const int sc = tid >> 3;          // 10 classes
      const int kc = tid & 7;           // 8-way K-split, shfl reduce
      const float* w = p.Wf2 + (size_t)t * HH * 10 + sc;
      float acc = 0.f;
#pragma unroll
      for (int k = kc; k < HH; k += 8) acc += ald[k] * w[(size_t)k * 10];
      acc += __shfl_xor(acc, 1);
      acc += __shfl_xor(acc, 2);
      acc += __shfl_xor(acc, 4);
      if (kc == 0)
        p.out[(size_t)b * 1000 + sc * 100 + t] = acc + p.bf2[t * 10 + sc];
    }
    // no sync needed: next writer of ald is ph8 (many syncs away)
  }
}

extern "C" void kernel_launch(void* const* d_in, const int* in_sizes, int n_in,
                              void* d_out, int out_size, void* d_ws, size_t ws_size,
                              hipStream_t stream) {
  (void)in_sizes; (void)n_in; (void)out_size; (void)d_ws; (void)ws_size;
  Params p;
  p.x   = (const float*)d_in[0];
  p.gum = (const float*)d_in[1];
  p.W1  = (const float*)d_in[2];  p.b1  = (const float*)d_in[3];
  p.W2  = (const float*)d_in[4];  p.b2  = (const float*)d_in[5];
  p.W3  = (const float*)d_in[6];  p.b3  = (const float*)d_in[7];
  p.W4  = (const float*)d_in[8];  p.b4  = (const float*)d_in[9];
  p.Wf2 = (const float*)d_in[10]; p.bf2 = (const float*)d_in[11];
  p.Wg1 = (const float*)d_in[12]; p.bg1 = (const float*)d_in[13];
  p.Wg2 = (const float*)d_in[14]; p.bg2 = (const float*)d_in[15];
  p.Wih = (const float*)d_in[16]; p.Whh = (const float*)d_in[17];
  p.bih = (const float*)d_in[18]; p.bhh = (const float*)d_in[19];
  p.out = (float*)d_out;
  hipLaunchKernelGGL(net_kernel, dim3(BB), dim3(NT), 0, stream, p);
}